// Round 11
// baseline (20446.626 us; speedup 1.0000x reference)
//
#include <hip/hip_runtime.h>
#include <hip/hip_fp16.h>
#include <math.h>

#define NB   32
#define LD   256
#define LE   258
#define HID  512
#define H3   1536
#define MLP  256
#define NL   4

typedef _Float16 h2 __attribute__((ext_vector_type(2)));

// ---------- init: zero h transport buffer (every launch, graph-safe) ----------
__global__ void k_init(uint32_t* __restrict__ hb){
  int i = blockIdx.x*256 + threadIdx.x;
  if (i < 2*NB*HID) hb[i] = 0u;   // tag 0; first wants start at 1 -> never match
}

// ---------------- GRU: 128 WGs = 32 batches x 4 slices ----------------
// 384 threads/WG (6 waves, 2/SIMD at 256 VGPR), 1 gate-row per thread,
// weights f16x2 register-resident. h fp32 with 8-bit UNIQUE step tag in
// mantissa LSBs (round-10 proven). Own slice goes straight to LDS; each
// thread polls exactly ONE foreign word (single round-trip detect).
__global__ __launch_bounds__(384,1)
void k_gru(const float* __restrict__ GI, const float* __restrict__ W_hh,
           const float* __restrict__ b_hh, const float* __restrict__ h0,
           float* __restrict__ dout,
           uint32_t* __restrict__ hbuf){    // 2*NB*HID u32 (double buffer)
  const int wg  = blockIdx.x;
  const int b   = wg & 31, g = wg >> 5;     // slice g in [0,4)
  const int tid = threadIdx.x;              // 0..383
  const int sect = tid >> 7;                // 0=r, 1=z, 2=n
  const int u    = tid & 127;               // local hidden unit within slice
  const int c    = sect*HID + g*128 + u;    // gate row in [0,1536)

  __shared__ __align__(16) float h_lds[HID];
  __shared__ float zs[128], gs[128], ns[128];

  // --- prologue: W_hh[c][:] -> 256 f16x2 VGPRs (one-time, static indexing) ---
  h2 w[256];
  const float4* wr = (const float4*)(W_hh + (size_t)c*HID);
  #pragma unroll
  for (int i=0;i<128;i++){
    float4 v = wr[i];
    h2 p0; p0[0]=(_Float16)v.x; p0[1]=(_Float16)v.y;
    h2 p1; p1[0]=(_Float16)v.z; p1[1]=(_Float16)v.w;
    w[2*i] = p0; w[2*i+1] = p1;
  }
  const float bh = b_hh[c];
  float h_old = (tid < 128) ? h0[(size_t)b*HID + g*128 + u] : 0.f;
  const float* gi_base = GI + (size_t)b*LD*H3 + c;
  float* db = dout + (size_t)b*LD*HID + g*128;

  // each thread polls exactly one FOREIGN word (skip own slice [g*128,(g+1)*128))
  const int widx = (tid < g*128) ? tid : tid + 128;

  // initial h_0 straight from h0 (fp32, plain loads)
  for (int i=tid;i<HID;i+=384) h_lds[i] = h0[(size_t)b*HID + i];
  __syncthreads();

  float gi = gi_base[0];                      // GI for step 0
  for (int t=0;t<LD;t++){
    // gh[c] = sum_k W_hh[c][k] * h[k]  (f16 weight, fp32 h, 4 indep accums)
    float a0=0.f, a1=0.f, a2=0.f, a3=0.f;
    const float4* hl = (const float4*)h_lds;
    #pragma unroll
    for (int kk=0;kk<128;kk++){
      float4 hv = hl[kk];
      h2 q0 = w[2*kk], q1 = w[2*kk+1];
      a0 = fmaf((float)q0[0], hv.x, a0);
      a1 = fmaf((float)q0[1], hv.y, a1);
      a2 = fmaf((float)q1[0], hv.z, a2);
      a3 = fmaf((float)q1[1], hv.w, a3);
    }
    float hh = (a0+a1) + (a2+a3) + bh;
    if (sect==1)      zs[u] = gi + hh;
    else if (sect==2){ gs[u] = gi; ns[u] = hh; }
    float pre_r = gi + hh;                     // valid for sect==0
    __syncthreads();                           // SYNC1: zs/gs/ns ready, dots done

    if (t < LD-1){
      uint32_t* hb = hbuf + (size_t)((t+1)&1)*(NB*HID) + (size_t)b*HID;
      const uint32_t want = (uint32_t)(t+1) & 0xFFu;   // unique per run
      if (tid < 128){
        float r = __builtin_amdgcn_rcpf(1.f + __expf(-pre_r));
        float z = __builtin_amdgcn_rcpf(1.f + __expf(-zs[u]));
        float x = gs[u] + r*ns[u];
        float e2 = __expf(2.f*x);
        float n = 1.f - 2.f*__builtin_amdgcn_rcpf(e2 + 1.f);   // tanh
        float hnew = (1.f-z)*n + z*h_old;
        h_old = hnew;
        uint32_t wb = (__builtin_bit_cast(uint32_t, hnew) & ~0xFFu) | want;
        // own slice straight to LDS (no global round-trip for self)
        h_lds[g*128 + u] = __builtin_bit_cast(float, wb);
        __hip_atomic_store(hb + g*128 + u, wb,
                           __ATOMIC_RELAXED, __HIP_MEMORY_SCOPE_AGENT);
        db[(size_t)t*HID + u] = hnew;          // off critical path
      }
      float gnext = gi_base[(size_t)(t+1)*H3]; // prefetch next-step GI
      // poll ONE foreign word per thread (single round-trip detect)
      {
        const uint32_t* p = hb + widx;
        int it = 0;
        for (;;){
          uint32_t x = __hip_atomic_load(p, __ATOMIC_RELAXED, __HIP_MEMORY_SCOPE_AGENT);
          if ((x & 0xFFu) == want){ h_lds[widx] = __builtin_bit_cast(float, x); break; }
          if (++it >= (1<<20)) break;
          __builtin_amdgcn_s_sleep(1);
        }
      }
      __syncthreads();                         // SYNC2: h_lds fully fresh
      gi = gnext;
    } else {
      if (tid < 128){
        float r = __builtin_amdgcn_rcpf(1.f + __expf(-pre_r));
        float z = __builtin_amdgcn_rcpf(1.f + __expf(-zs[u]));
        float x = gs[u] + r*ns[u];
        float e2 = __expf(2.f*x);
        float n = 1.f - 2.f*__builtin_amdgcn_rcpf(e2 + 1.f);
        float hnew = (1.f-z)*n + z*h_old;
        db[(size_t)t*HID + u] = hnew;
      }
    }
  }
}

// ---------- generic NT gemm: C[M,N] = A[M,K] @ B[N,K]^T (+bias)(+relu) ------
template<int BIAS, int RELU>
__global__ __launch_bounds__(256)
void k_gemm_nt(const float* __restrict__ A, const float* __restrict__ Bm,
               const float* __restrict__ bias, float* __restrict__ C,
               int M, int N, int K){
  __shared__ float As[32][68];
  __shared__ float Bs[32][68];
  const int bm = blockIdx.y*64, bn = blockIdx.x*64;
  const int tid = threadIdx.x;
  const int tx = tid & 15, ty = tid >> 4;
  const int lr = tid >> 3;
  const int lk = (tid & 7) << 2;
  const float* A0 = A + (size_t)(bm+lr)*K + lk;
  const float* A1 = A + (size_t)(bm+lr+32)*K + lk;
  const float* B0 = Bm + (size_t)(bn+lr)*K + lk;
  const float* B1 = Bm + (size_t)(bn+lr+32)*K + lk;
  float acc[4][4] = {};
  for (int k0=0;k0<K;k0+=32){
    float4 a0 = *(const float4*)(A0 + k0);
    float4 a1 = *(const float4*)(A1 + k0);
    float4 b0 = *(const float4*)(B0 + k0);
    float4 b1 = *(const float4*)(B1 + k0);
    __syncthreads();
    As[lk+0][lr]=a0.x; As[lk+1][lr]=a0.y; As[lk+2][lr]=a0.z; As[lk+3][lr]=a0.w;
    As[lk+0][lr+32]=a1.x; As[lk+1][lr+32]=a1.y; As[lk+2][lr+32]=a1.z; As[lk+3][lr+32]=a1.w;
    Bs[lk+0][lr]=b0.x; Bs[lk+1][lr]=b0.y; Bs[lk+2][lr]=b0.z; Bs[lk+3][lr]=b0.w;
    Bs[lk+0][lr+32]=b1.x; Bs[lk+1][lr+32]=b1.y; Bs[lk+2][lr+32]=b1.z; Bs[lk+3][lr+32]=b1.w;
    __syncthreads();
    #pragma unroll
    for (int kk=0;kk<32;kk++){
      float4 av = *(const float4*)&As[kk][ty<<2];
      float4 bv = *(const float4*)&Bs[kk][tx<<2];
      float a4[4] = {av.x,av.y,av.z,av.w};
      float b4[4] = {bv.x,bv.y,bv.z,bv.w};
      #pragma unroll
      for (int i=0;i<4;i++)
        #pragma unroll
        for (int j=0;j<4;j++)
          acc[i][j] = fmaf(a4[i], b4[j], acc[i][j]);
    }
  }
  #pragma unroll
  for (int i=0;i<4;i++){
    int m = bm + (ty<<2) + i;
    #pragma unroll
    for (int j=0;j<4;j++){
      int n = bn + (tx<<2) + j;
      float v = acc[i][j];
      if (BIAS) v += bias[n];
      if (RELU) v = fmaxf(v, 0.f);
      C[(size_t)m*N + n] = v;
    }
  }
}

// ---------- NN gemm (batched over l): T[l][b][d][k] = d_h @ U[l] ----------
__global__ __launch_bounds__(256)
void k_gemm_nn_T(const float* __restrict__ A, const float* __restrict__ U,
                 float* __restrict__ T){
  __shared__ float As[32][68];
  __shared__ float Bs[32][68];
  const int l = blockIdx.z;
  const float* Bm = U + (size_t)l*MLP*MLP;
  float* C = T + (size_t)l*NB*LD*MLP;
  const int bm = blockIdx.y*64, bn = blockIdx.x*64;
  const int tid = threadIdx.x;
  const int tx = tid & 15, ty = tid >> 4;
  const int lr = tid >> 3;
  const int lk = (tid & 7) << 2;
  const int bk_r = tid >> 4;
  const int bn_c = (tid & 15) << 2;
  const float* A0 = A + (size_t)(bm+lr)*MLP + lk;
  const float* A1 = A + (size_t)(bm+lr+32)*MLP + lk;
  float acc[4][4] = {};
  for (int k0=0;k0<MLP;k0+=32){
    float4 a0 = *(const float4*)(A0 + k0);
    float4 a1 = *(const float4*)(A1 + k0);
    float4 u0 = *(const float4*)(Bm + (size_t)(k0+bk_r)*MLP + bn + bn_c);
    float4 u1 = *(const float4*)(Bm + (size_t)(k0+bk_r+16)*MLP + bn + bn_c);
    __syncthreads();
    As[lk+0][lr]=a0.x; As[lk+1][lr]=a0.y; As[lk+2][lr]=a0.z; As[lk+3][lr]=a0.w;
    As[lk+0][lr+32]=a1.x; As[lk+1][lr+32]=a1.y; As[lk+2][lr+32]=a1.z; As[lk+3][lr+32]=a1.w;
    *(float4*)&Bs[bk_r][bn_c]    = u0;
    *(float4*)&Bs[bk_r+16][bn_c] = u1;
    __syncthreads();
    #pragma unroll
    for (int kk=0;kk<32;kk++){
      float4 av = *(const float4*)&As[kk][ty<<2];
      float4 bv = *(const float4*)&Bs[kk][tx<<2];
      float a4[4] = {av.x,av.y,av.z,av.w};
      float b4[4] = {bv.x,bv.y,bv.z,bv.w};
      #pragma unroll
      for (int i=0;i<4;i++)
        #pragma unroll
        for (int j=0;j<4;j++)
          acc[i][j] = fmaf(a4[i], b4[j], acc[i][j]);
    }
  }
  #pragma unroll
  for (int i=0;i<4;i++){
    int m = bm + (ty<<2) + i;
    #pragma unroll
    for (int j=0;j<4;j++)
      C[(size_t)m*MLP + bn + (tx<<2) + j] = acc[i][j];
  }
}

// -------- s_e / s_d: S[b][l][r] = dot(W[l], Hm[b,r,:]) --------
__global__ void k_bilinear(const float* __restrict__ W, const float* __restrict__ Hm,
                           float* __restrict__ S, int Lrows){
  int idx = blockIdx.x*256 + threadIdx.x;
  if (idx >= NB*Lrows) return;
  int b = idx / Lrows, r = idx - b*Lrows;
  const float* row = Hm + (size_t)idx*MLP;
  float acc[NL] = {0.f,0.f,0.f,0.f};
  for (int h=0; h<MLP; h+=4){
    float4 x = *(const float4*)(row + h);
    #pragma unroll
    for (int l=0;l<NL;l++){
      float4 w = *(const float4*)(W + l*MLP + h);
      acc[l] += x.x*w.x + x.y*w.y + x.z*w.z + x.w*w.w;
    }
  }
  #pragma unroll
  for (int l=0;l<NL;l++) S[((size_t)b*NL + l)*Lrows + r] = acc[l];
}

// -------- final: out[b,d,e,l] = T[l,b,d,:]·e_h[b,e,:] + s_d + s_e + b_aff --------
__global__ __launch_bounds__(256)
void k_s2(const float* __restrict__ T, const float* __restrict__ eh,
          const float* __restrict__ sd, const float* __restrict__ se,
          const float* __restrict__ baff, float* __restrict__ out){
  __shared__ float As[32][68];
  __shared__ float Bs[32][68];
  const int b = blockIdx.z;
  const int d0 = blockIdx.y*64, e0 = blockIdx.x*64;
  const int tid = threadIdx.x;
  const int tx = tid & 15, ty = tid >> 4;
  const int lr = tid >> 3;
  const int lk = (tid & 7) << 2;
  const float* EH = eh + (size_t)b*LE*MLP;
  for (int l=0;l<NL;l++){
    const float* A = T + ((size_t)(l*NB + b))*LD*MLP;
    float acc[4][4] = {};
    for (int k0=0;k0<MLP;k0+=32){
      float4 a0 = *(const float4*)(A + (size_t)(d0+lr)*MLP + k0 + lk);
      float4 a1 = *(const float4*)(A + (size_t)(d0+lr+32)*MLP + k0 + lk);
      float4 z4 = make_float4(0.f,0.f,0.f,0.f);
      int er0 = e0+lr, er1 = e0+lr+32;
      float4 b0 = (er0<LE) ? *(const float4*)(EH + (size_t)er0*MLP + k0 + lk) : z4;
      float4 b1 = (er1<LE) ? *(const float4*)(EH + (size_t)er1*MLP + k0 + lk) : z4;
      __syncthreads();
      As[lk+0][lr]=a0.x; As[lk+1][lr]=a0.y; As[lk+2][lr]=a0.z; As[lk+3][lr]=a0.w;
      As[lk+0][lr+32]=a1.x; As[lk+1][lr+32]=a1.y; As[lk+2][lr+32]=a1.z; As[lk+3][lr+32]=a1.w;
      Bs[lk+0][lr]=b0.x; Bs[lk+1][lr]=b0.y; Bs[lk+2][lr]=b0.z; Bs[lk+3][lr]=b0.w;
      Bs[lk+0][lr+32]=b1.x; Bs[lk+1][lr+32]=b1.y; Bs[lk+2][lr+32]=b1.z; Bs[lk+3][lr+32]=b1.w;
      __syncthreads();
      #pragma unroll
      for (int kk=0;kk<32;kk++){
        float4 av = *(const float4*)&As[kk][ty<<2];
        float4 bv = *(const float4*)&Bs[kk][tx<<2];
        float a4[4] = {av.x,av.y,av.z,av.w};
        float b4[4] = {bv.x,bv.y,bv.z,bv.w};
        #pragma unroll
        for (int i=0;i<4;i++)
          #pragma unroll
          for (int j=0;j<4;j++)
            acc[i][j] = fmaf(a4[i], b4[j], acc[i][j]);
      }
    }
    float bl = baff[l];
    float sdl[4], sel[4];
    #pragma unroll
    for (int i=0;i<4;i++) sdl[i] = sd[((size_t)b*NL + l)*LD + d0 + (ty<<2) + i];
    #pragma unroll
    for (int j=0;j<4;j++){
      int e = e0 + (tx<<2) + j;
      sel[j] = (e<LE) ? se[((size_t)b*NL + l)*LE + e] : 0.f;
    }
    #pragma unroll
    for (int i=0;i<4;i++){
      int d = d0 + (ty<<2) + i;
      #pragma unroll
      for (int j=0;j<4;j++){
        int e = e0 + (tx<<2) + j;
        if (e < LE)
          out[(((size_t)b*LD + d)*LE + e)*NL + l] = acc[i][j] + sdl[i] + sel[j] + bl;
      }
    }
  }
}

extern "C" void kernel_launch(void* const* d_in, const int* in_sizes, int n_in,
                              void* d_out, int out_size, void* d_ws, size_t ws_size,
                              hipStream_t stream){
  const float* e_outputs = (const float*)d_in[0];
  const float* d_inputs  = (const float*)d_in[1];
  const float* h0        = (const float*)d_in[2];
  const float* W_ih      = (const float*)d_in[3];
  const float* W_hh      = (const float*)d_in[4];
  const float* b_ih      = (const float*)d_in[5];
  const float* b_hh      = (const float*)d_in[6];
  const float* e_mlp_w   = (const float*)d_in[7];
  const float* e_mlp_b   = (const float*)d_in[8];
  const float* d_mlp_w   = (const float*)d_in[9];
  const float* d_mlp_b   = (const float*)d_in[10];
  const float* W_e       = (const float*)d_in[11];
  const float* W_d       = (const float*)d_in[12];
  const float* U         = (const float*)d_in[13];
  const float* b_aff     = (const float*)d_in[14];
  float* out = (float*)d_out;
  float* ws  = (float*)d_ws;

  // workspace layout (floats). T reuses GI's region (GI dead after k_gru).
  float* GI   = ws;                        // 32*256*1536 = 12,582,912
  float* T    = ws;                        // 4*32*256*256 = 8,388,608 (overlaps GI)
  uint32_t* hbuf = (uint32_t*)(ws + 12582912);  // 2*32*512 u32
  float* dout = ws   + 12582912 + 786432;  // 32*256*512 = 4,194,304
  float* eh   = dout + 4194304;            // 32*258*256 = 2,113,536
  float* dh   = eh   + 2113536;            // 32*256*256 = 2,097,152
  float* se   = dh   + 2097152;            // 32*4*258 = 33,024
  float* sd   = se   + 33024;              // 32*4*256 = 32,768

  k_init<<<dim3((2*NB*HID+255)/256), 256, 0, stream>>>(hbuf);
  // GI = d_inputs @ W_ih^T + b_ih   (M=8192,N=1536,K=512)
  k_gemm_nt<1,0><<<dim3(H3/64, (NB*LD)/64), 256, 0, stream>>>(d_inputs, W_ih, b_ih, GI, NB*LD, H3, HID);
  // e_h = relu(e_outputs @ e_mlp_w^T + b)  (M=8256,N=256,K=512)
  k_gemm_nt<1,1><<<dim3(MLP/64, (NB*LE)/64), 256, 0, stream>>>(e_outputs, e_mlp_w, e_mlp_b, eh, NB*LE, MLP, HID);
  // GRU recurrence -> d_outputs (4 slices/batch, 1-word poll, unique tags)
  k_gru<<<dim3(NB*4), 384, 0, stream>>>(GI, W_hh, b_hh, h0, dout, hbuf);
  // d_h = relu(d_outputs @ d_mlp_w^T + b)  (M=8192,N=256,K=512)
  k_gemm_nt<1,1><<<dim3(MLP/64, (NB*LD)/64), 256, 0, stream>>>(dout, d_mlp_w, d_mlp_b, dh, NB*LD, MLP, HID);
  // T[l] = d_h @ U[l]  (M=8192,N=256,K=256, batched over l)
  k_gemm_nn_T<<<dim3(MLP/64, (NB*LD)/64, NL), 256, 0, stream>>>(dh, U, T);
  // s_e, s_d
  k_bilinear<<<dim3((NB*LE+255)/256), 256, 0, stream>>>(W_e, eh, se, LE);
  k_bilinear<<<dim3((NB*LD+255)/256), 256, 0, stream>>>(W_d, dh, sd, LD);
  // out[b,d,e,l] = T[l,b,d,:]·e_h[b,e,:] + s_d + s_e + b_aff
  k_s2<<<dim3(5, LD/64, NB), 256, 0, stream>>>(T, eh, sd, se, b_aff, out);
}

// Round 12
// 2559.317 us; speedup vs baseline: 7.9891x; 7.9891x over previous
//
#include <hip/hip_runtime.h>
#include <hip/hip_fp16.h>
#include <math.h>

#define NB   32
#define LD   256
#define LE   258
#define HID  512
#define H3   1536
#define MLP  256
#define NL   4

typedef _Float16 h2 __attribute__((ext_vector_type(2)));

// ---------- init: zero h transport buffer (every launch, graph-safe) ----------
__global__ void k_init(uint32_t* __restrict__ hb){
  int i = blockIdx.x*256 + threadIdx.x;
  if (i < 2*NB*HID) hb[i] = 0u;   // tag 0; first wants start at 1 -> never match
}

// ---------------- GRU: 256 WGs = 32 batches x 8 slices ----------------
// Round-7 structure (measured 2050us, absmax 0.125) + round-10's 8-bit
// UNIQUE step tags (provably stale-proof). 192 threads/WG (3 waves -> 256
// VGPR verified no-spill), 1 gate-row per thread, f16x2 weights register-
// resident, h fp32, pure agent-scope relaxed tagged-payload sync.
__global__ __launch_bounds__(192,1)
void k_gru(const float* __restrict__ GI, const float* __restrict__ W_hh,
           const float* __restrict__ b_hh, const float* __restrict__ h0,
           float* __restrict__ dout,
           uint32_t* __restrict__ hbuf){    // 2*NB*HID u32 (double buffer)
  const int wg  = blockIdx.x;
  const int b   = wg >> 3, g = wg & 7;
  const int tid = threadIdx.x;
  const int sect = tid >> 6;                  // 0=r, 1=z, 2=n
  const int u    = tid & 63;
  const int c    = sect*HID + g*64 + u;       // gate row in [0,1536)

  __shared__ __align__(16) float h_lds[HID];
  __shared__ float zs[64], gs[64], ns[64];

  // --- prologue: W_hh[c][:] -> 256 f16x2 VGPRs (one-time, static indexing) ---
  h2 w[256];
  const float4* wr = (const float4*)(W_hh + (size_t)c*HID);
  #pragma unroll
  for (int i=0;i<128;i++){
    float4 v = wr[i];
    h2 p0; p0[0]=(_Float16)v.x; p0[1]=(_Float16)v.y;
    h2 p1; p1[0]=(_Float16)v.z; p1[1]=(_Float16)v.w;
    w[2*i] = p0; w[2*i+1] = p1;
  }
  const float bh = b_hh[c];
  float h_old = (tid < 64) ? h0[(size_t)b*HID + g*64 + u] : 0.f;
  const float* gi_base = GI + (size_t)b*LD*H3 + c;
  float* db = dout + (size_t)b*LD*HID + g*64;

  // reader word set: w0 covers 0..191, w1 192..383, w2 384..511 (tid<128)
  const int w0 = tid, w1 = tid + 192, w2 = tid + 384;

  // initial h_0 straight from h0 (fp32, plain loads)
  for (int i=tid;i<HID;i+=192) h_lds[i] = h0[(size_t)b*HID + i];
  __syncthreads();

  float gi = gi_base[0];                      // GI for step 0
  for (int t=0;t<LD;t++){
    // gh[c] = sum_k W_hh[c][k] * h[k]  (f16 weight, fp32 h, 4 indep accums)
    float a0=0.f, a1=0.f, a2=0.f, a3=0.f;
    const float4* hl = (const float4*)h_lds;
    #pragma unroll
    for (int kk=0;kk<128;kk++){
      float4 hv = hl[kk];
      h2 q0 = w[2*kk], q1 = w[2*kk+1];
      a0 = fmaf((float)q0[0], hv.x, a0);
      a1 = fmaf((float)q0[1], hv.y, a1);
      a2 = fmaf((float)q1[0], hv.z, a2);
      a3 = fmaf((float)q1[1], hv.w, a3);
    }
    float hh = (a0+a1) + (a2+a3) + bh;
    if (sect==1)      zs[u] = gi + hh;
    else if (sect==2){ gs[u] = gi; ns[u] = hh; }
    float pre_r = gi + hh;                     // valid for sect==0
    __syncthreads();                           // SYNC1: zs/gs/ns ready, dots done

    if (t < LD-1){
      uint32_t* hb = hbuf + (size_t)((t+1)&1)*(NB*HID) + (size_t)b*HID;
      const uint32_t want = (uint32_t)(t+1) & 0xFFu;   // unique per run
      if (tid < 64){
        float r = __builtin_amdgcn_rcpf(1.f + __expf(-pre_r));
        float z = __builtin_amdgcn_rcpf(1.f + __expf(-zs[u]));
        float x = gs[u] + r*ns[u];
        float e2 = __expf(2.f*x);
        float n = 1.f - 2.f*__builtin_amdgcn_rcpf(e2 + 1.f);   // tanh
        float hnew = (1.f-z)*n + z*h_old;
        h_old = hnew;
        uint32_t wb = (__builtin_bit_cast(uint32_t, hnew) & ~0xFFu) | want;
        __hip_atomic_store(hb + g*64 + u, wb,
                           __ATOMIC_RELAXED, __HIP_MEMORY_SCOPE_AGENT);
        db[(size_t)t*HID + u] = hnew;          // off critical path
      }
      float gnext = gi_base[(size_t)(t+1)*H3]; // prefetch next-step GI
      // poll the payload itself (unique tag check), write straight to LDS
      uint32_t* hlu = (uint32_t*)h_lds;
      bool n0 = true, n1 = true, n2 = (w2 < HID);
      int it = 0;
      while ((n0 | n1 | n2) && it < (1<<20)){
        if (n0){
          uint32_t x = __hip_atomic_load(hb+w0, __ATOMIC_RELAXED, __HIP_MEMORY_SCOPE_AGENT);
          if ((x & 0xFFu) == want){ hlu[w0] = x; n0 = false; }
        }
        if (n1){
          uint32_t x = __hip_atomic_load(hb+w1, __ATOMIC_RELAXED, __HIP_MEMORY_SCOPE_AGENT);
          if ((x & 0xFFu) == want){ hlu[w1] = x; n1 = false; }
        }
        if (n2){
          uint32_t x = __hip_atomic_load(hb+w2, __ATOMIC_RELAXED, __HIP_MEMORY_SCOPE_AGENT);
          if ((x & 0xFFu) == want){ hlu[w2] = x; n2 = false; }
        }
        if (n0 | n1 | n2){ ++it; __builtin_amdgcn_s_sleep(1); }
      }
      __syncthreads();                         // SYNC2: h_lds fully fresh
      gi = gnext;
    } else {
      if (tid < 64){
        float r = __builtin_amdgcn_rcpf(1.f + __expf(-pre_r));
        float z = __builtin_amdgcn_rcpf(1.f + __expf(-zs[u]));
        float x = gs[u] + r*ns[u];
        float e2 = __expf(2.f*x);
        float n = 1.f - 2.f*__builtin_amdgcn_rcpf(e2 + 1.f);
        float hnew = (1.f-z)*n + z*h_old;
        db[(size_t)t*HID + u] = hnew;
      }
    }
  }
}

// ---- big NT gemm: C[M,N] = A[M,K]@B[N,K]^T (+bias)(+relu), 128x128 tile ----
// 256 threads, 8x8 micro-tile, BK=16. Requires M%128==0, N%128==0, K%16==0.
template<int BIAS, int RELU>
__global__ __launch_bounds__(256)
void k_gemm_nt128(const float* __restrict__ A, const float* __restrict__ Bm,
                  const float* __restrict__ bias, float* __restrict__ C,
                  int M, int N, int K){
  __shared__ float As[16][132];
  __shared__ float Bs[16][132];
  const int bm = blockIdx.y*128, bn = blockIdx.x*128;
  const int tid = threadIdx.x;
  const int tx = tid & 15, ty = tid >> 4;      // 16x16 thread grid
  const int lr = tid >> 1;                     // 0..127 load row
  const int lc = (tid & 1) << 3;               // 0 or 8
  const float* Ap = A + (size_t)(bm+lr)*K + lc;
  const float* Bp = Bm + (size_t)(bn+lr)*K + lc;
  float acc[8][8] = {};
  for (int k0=0;k0<K;k0+=16){
    float4 a0 = *(const float4*)(Ap + k0);
    float4 a1 = *(const float4*)(Ap + k0 + 4);
    float4 b0 = *(const float4*)(Bp + k0);
    float4 b1 = *(const float4*)(Bp + k0 + 4);
    __syncthreads();
    As[lc+0][lr]=a0.x; As[lc+1][lr]=a0.y; As[lc+2][lr]=a0.z; As[lc+3][lr]=a0.w;
    As[lc+4][lr]=a1.x; As[lc+5][lr]=a1.y; As[lc+6][lr]=a1.z; As[lc+7][lr]=a1.w;
    Bs[lc+0][lr]=b0.x; Bs[lc+1][lr]=b0.y; Bs[lc+2][lr]=b0.z; Bs[lc+3][lr]=b0.w;
    Bs[lc+4][lr]=b1.x; Bs[lc+5][lr]=b1.y; Bs[lc+6][lr]=b1.z; Bs[lc+7][lr]=b1.w;
    __syncthreads();
    #pragma unroll
    for (int kk=0;kk<16;kk++){
      float4 va0 = *(const float4*)&As[kk][ty<<3];
      float4 va1 = *(const float4*)&As[kk][(ty<<3)+4];
      float4 vb0 = *(const float4*)&Bs[kk][tx<<3];
      float4 vb1 = *(const float4*)&Bs[kk][(tx<<3)+4];
      float a8[8] = {va0.x,va0.y,va0.z,va0.w,va1.x,va1.y,va1.z,va1.w};
      float b8[8] = {vb0.x,vb0.y,vb0.z,vb0.w,vb1.x,vb1.y,vb1.z,vb1.w};
      #pragma unroll
      for (int i=0;i<8;i++)
        #pragma unroll
        for (int j=0;j<8;j++)
          acc[i][j] = fmaf(a8[i], b8[j], acc[i][j]);
    }
  }
  #pragma unroll
  for (int i=0;i<8;i++){
    int m = bm + (ty<<3) + i;
    #pragma unroll
    for (int j=0;j<8;j++){
      int n = bn + (tx<<3) + j;
      float v = acc[i][j];
      if (BIAS) v += bias[n];
      if (RELU) v = fmaxf(v, 0.f);
      C[(size_t)m*N + n] = v;
    }
  }
}

// ---------- generic NT gemm (64x64): used where M%128 != 0 (e_h) ----------
template<int BIAS, int RELU>
__global__ __launch_bounds__(256)
void k_gemm_nt(const float* __restrict__ A, const float* __restrict__ Bm,
               const float* __restrict__ bias, float* __restrict__ C,
               int M, int N, int K){
  __shared__ float As[32][68];
  __shared__ float Bs[32][68];
  const int bm = blockIdx.y*64, bn = blockIdx.x*64;
  const int tid = threadIdx.x;
  const int tx = tid & 15, ty = tid >> 4;
  const int lr = tid >> 3;
  const int lk = (tid & 7) << 2;
  const float* A0 = A + (size_t)(bm+lr)*K + lk;
  const float* A1 = A + (size_t)(bm+lr+32)*K + lk;
  const float* B0 = Bm + (size_t)(bn+lr)*K + lk;
  const float* B1 = Bm + (size_t)(bn+lr+32)*K + lk;
  float acc[4][4] = {};
  for (int k0=0;k0<K;k0+=32){
    float4 a0 = *(const float4*)(A0 + k0);
    float4 a1 = *(const float4*)(A1 + k0);
    float4 b0 = *(const float4*)(B0 + k0);
    float4 b1 = *(const float4*)(B1 + k0);
    __syncthreads();
    As[lk+0][lr]=a0.x; As[lk+1][lr]=a0.y; As[lk+2][lr]=a0.z; As[lk+3][lr]=a0.w;
    As[lk+0][lr+32]=a1.x; As[lk+1][lr+32]=a1.y; As[lk+2][lr+32]=a1.z; As[lk+3][lr+32]=a1.w;
    Bs[lk+0][lr]=b0.x; Bs[lk+1][lr]=b0.y; Bs[lk+2][lr]=b0.z; Bs[lk+3][lr]=b0.w;
    Bs[lk+0][lr+32]=b1.x; Bs[lk+1][lr+32]=b1.y; Bs[lk+2][lr+32]=b1.z; Bs[lk+3][lr+32]=b1.w;
    __syncthreads();
    #pragma unroll
    for (int kk=0;kk<32;kk++){
      float4 av = *(const float4*)&As[kk][ty<<2];
      float4 bv = *(const float4*)&Bs[kk][tx<<2];
      float a4[4] = {av.x,av.y,av.z,av.w};
      float b4[4] = {bv.x,bv.y,bv.z,bv.w};
      #pragma unroll
      for (int i=0;i<4;i++)
        #pragma unroll
        for (int j=0;j<4;j++)
          acc[i][j] = fmaf(a4[i], b4[j], acc[i][j]);
    }
  }
  #pragma unroll
  for (int i=0;i<4;i++){
    int m = bm + (ty<<2) + i;
    #pragma unroll
    for (int j=0;j<4;j++){
      int n = bn + (tx<<2) + j;
      float v = acc[i][j];
      if (BIAS) v += bias[n];
      if (RELU) v = fmaxf(v, 0.f);
      C[(size_t)m*N + n] = v;
    }
  }
}

// ---------- NN gemm (batched over l): T[l][b][d][k] = d_h @ U[l] ----------
__global__ __launch_bounds__(256)
void k_gemm_nn_T(const float* __restrict__ A, const float* __restrict__ U,
                 float* __restrict__ T){
  __shared__ float As[32][68];
  __shared__ float Bs[32][68];
  const int l = blockIdx.z;
  const float* Bm = U + (size_t)l*MLP*MLP;
  float* C = T + (size_t)l*NB*LD*MLP;
  const int bm = blockIdx.y*64, bn = blockIdx.x*64;
  const int tid = threadIdx.x;
  const int tx = tid & 15, ty = tid >> 4;
  const int lr = tid >> 3;
  const int lk = (tid & 7) << 2;
  const int bk_r = tid >> 4;
  const int bn_c = (tid & 15) << 2;
  const float* A0 = A + (size_t)(bm+lr)*MLP + lk;
  const float* A1 = A + (size_t)(bm+lr+32)*MLP + lk;
  float acc[4][4] = {};
  for (int k0=0;k0<MLP;k0+=32){
    float4 a0 = *(const float4*)(A0 + k0);
    float4 a1 = *(const float4*)(A1 + k0);
    float4 u0 = *(const float4*)(Bm + (size_t)(k0+bk_r)*MLP + bn + bn_c);
    float4 u1 = *(const float4*)(Bm + (size_t)(k0+bk_r+16)*MLP + bn + bn_c);
    __syncthreads();
    As[lk+0][lr]=a0.x; As[lk+1][lr]=a0.y; As[lk+2][lr]=a0.z; As[lk+3][lr]=a0.w;
    As[lk+0][lr+32]=a1.x; As[lk+1][lr+32]=a1.y; As[lk+2][lr+32]=a1.z; As[lk+3][lr+32]=a1.w;
    *(float4*)&Bs[bk_r][bn_c]    = u0;
    *(float4*)&Bs[bk_r+16][bn_c] = u1;
    __syncthreads();
    #pragma unroll
    for (int kk=0;kk<32;kk++){
      float4 av = *(const float4*)&As[kk][ty<<2];
      float4 bv = *(const float4*)&Bs[kk][tx<<2];
      float a4[4] = {av.x,av.y,av.z,av.w};
      float b4[4] = {bv.x,bv.y,bv.z,bv.w};
      #pragma unroll
      for (int i=0;i<4;i++)
        #pragma unroll
        for (int j=0;j<4;j++)
          acc[i][j] = fmaf(a4[i], b4[j], acc[i][j]);
    }
  }
  #pragma unroll
  for (int i=0;i<4;i++){
    int m = bm + (ty<<2) + i;
    #pragma unroll
    for (int j=0;j<4;j++)
      C[(size_t)m*MLP + bn + (tx<<2) + j] = acc[i][j];
  }
}

// -------- s_e / s_d: S[b][l][r] = dot(W[l], Hm[b,r,:]) --------
__global__ void k_bilinear(const float* __restrict__ W, const float* __restrict__ Hm,
                           float* __restrict__ S, int Lrows){
  int idx = blockIdx.x*256 + threadIdx.x;
  if (idx >= NB*Lrows) return;
  int b = idx / Lrows, r = idx - b*Lrows;
  const float* row = Hm + (size_t)idx*MLP;
  float acc[NL] = {0.f,0.f,0.f,0.f};
  for (int h=0; h<MLP; h+=4){
    float4 x = *(const float4*)(row + h);
    #pragma unroll
    for (int l=0;l<NL;l++){
      float4 w = *(const float4*)(W + l*MLP + h);
      acc[l] += x.x*w.x + x.y*w.y + x.z*w.z + x.w*w.w;
    }
  }
  #pragma unroll
  for (int l=0;l<NL;l++) S[((size_t)b*NL + l)*Lrows + r] = acc[l];
}

// -------- final: out[b,d,e,l] = T[l,b,d,:]·e_h[b,e,:] + s_d + s_e + b_aff --------
__global__ __launch_bounds__(256)
void k_s2(const float* __restrict__ T, const float* __restrict__ eh,
          const float* __restrict__ sd, const float* __restrict__ se,
          const float* __restrict__ baff, float* __restrict__ out){
  __shared__ float As[32][68];
  __shared__ float Bs[32][68];
  const int b = blockIdx.z;
  const int d0 = blockIdx.y*64, e0 = blockIdx.x*64;
  const int tid = threadIdx.x;
  const int tx = tid & 15, ty = tid >> 4;
  const int lr = tid >> 3;
  const int lk = (tid & 7) << 2;
  const float* EH = eh + (size_t)b*LE*MLP;
  for (int l=0;l<NL;l++){
    const float* A = T + ((size_t)(l*NB + b))*LD*MLP;
    float acc[4][4] = {};
    for (int k0=0;k0<MLP;k0+=32){
      float4 a0 = *(const float4*)(A + (size_t)(d0+lr)*MLP + k0 + lk);
      float4 a1 = *(const float4*)(A + (size_t)(d0+lr+32)*MLP + k0 + lk);
      float4 z4 = make_float4(0.f,0.f,0.f,0.f);
      int er0 = e0+lr, er1 = e0+lr+32;
      float4 b0 = (er0<LE) ? *(const float4*)(EH + (size_t)er0*MLP + k0 + lk) : z4;
      float4 b1 = (er1<LE) ? *(const float4*)(EH + (size_t)er1*MLP + k0 + lk) : z4;
      __syncthreads();
      As[lk+0][lr]=a0.x; As[lk+1][lr]=a0.y; As[lk+2][lr]=a0.z; As[lk+3][lr]=a0.w;
      As[lk+0][lr+32]=a1.x; As[lk+1][lr+32]=a1.y; As[lk+2][lr+32]=a1.z; As[lk+3][lr+32]=a1.w;
      Bs[lk+0][lr]=b0.x; Bs[lk+1][lr]=b0.y; Bs[lk+2][lr]=b0.z; Bs[lk+3][lr]=b0.w;
      Bs[lk+0][lr+32]=b1.x; Bs[lk+1][lr+32]=b1.y; Bs[lk+2][lr+32]=b1.z; Bs[lk+3][lr+32]=b1.w;
      __syncthreads();
      #pragma unroll
      for (int kk=0;kk<32;kk++){
        float4 av = *(const float4*)&As[kk][ty<<2];
        float4 bv = *(const float4*)&Bs[kk][tx<<2];
        float a4[4] = {av.x,av.y,av.z,av.w};
        float b4[4] = {bv.x,bv.y,bv.z,bv.w};
        #pragma unroll
        for (int i=0;i<4;i++)
          #pragma unroll
          for (int j=0;j<4;j++)
            acc[i][j] = fmaf(a4[i], b4[j], acc[i][j]);
      }
    }
    float bl = baff[l];
    float sdl[4], sel[4];
    #pragma unroll
    for (int i=0;i<4;i++) sdl[i] = sd[((size_t)b*NL + l)*LD + d0 + (ty<<2) + i];
    #pragma unroll
    for (int j=0;j<4;j++){
      int e = e0 + (tx<<2) + j;
      sel[j] = (e<LE) ? se[((size_t)b*NL + l)*LE + e] : 0.f;
    }
    #pragma unroll
    for (int i=0;i<4;i++){
      int d = d0 + (ty<<2) + i;
      #pragma unroll
      for (int j=0;j<4;j++){
        int e = e0 + (tx<<2) + j;
        if (e < LE)
          out[(((size_t)b*LD + d)*LE + e)*NL + l] = acc[i][j] + sdl[i] + sel[j] + bl;
      }
    }
  }
}

extern "C" void kernel_launch(void* const* d_in, const int* in_sizes, int n_in,
                              void* d_out, int out_size, void* d_ws, size_t ws_size,
                              hipStream_t stream){
  const float* e_outputs = (const float*)d_in[0];
  const float* d_inputs  = (const float*)d_in[1];
  const float* h0        = (const float*)d_in[2];
  const float* W_ih      = (const float*)d_in[3];
  const float* W_hh      = (const float*)d_in[4];
  const float* b_ih      = (const float*)d_in[5];
  const float* b_hh      = (const float*)d_in[6];
  const float* e_mlp_w   = (const float*)d_in[7];
  const float* e_mlp_b   = (const float*)d_in[8];
  const float* d_mlp_w   = (const float*)d_in[9];
  const float* d_mlp_b   = (const float*)d_in[10];
  const float* W_e       = (const float*)d_in[11];
  const float* W_d       = (const float*)d_in[12];
  const float* U         = (const float*)d_in[13];
  const float* b_aff     = (const float*)d_in[14];
  float* out = (float*)d_out;
  float* ws  = (float*)d_ws;

  // workspace layout (floats). T reuses GI's region (GI dead after k_gru).
  float* GI   = ws;                        // 32*256*1536 = 12,582,912
  float* T    = ws;                        // 4*32*256*256 = 8,388,608 (overlaps GI)
  uint32_t* hbuf = (uint32_t*)(ws + 12582912);  // 2*32*512 u32
  float* dout = ws   + 12582912 + 786432;  // 32*256*512 = 4,194,304
  float* eh   = dout + 4194304;            // 32*258*256 = 2,113,536
  float* dh   = eh   + 2113536;            // 32*256*256 = 2,097,152
  float* se   = dh   + 2097152;            // 32*4*258 = 33,024
  float* sd   = se   + 33024;              // 32*4*256 = 32,768

  k_init<<<dim3((2*NB*HID+255)/256), 256, 0, stream>>>(hbuf);
  // GI = d_inputs @ W_ih^T + b_ih   (M=8192,N=1536,K=512) -- 128-tile
  k_gemm_nt128<1,0><<<dim3(H3/128, (NB*LD)/128), 256, 0, stream>>>(d_inputs, W_ih, b_ih, GI, NB*LD, H3, HID);
  // e_h = relu(e_outputs @ e_mlp_w^T + b)  (M=8256,N=256,K=512) -- 64-tile (M%128!=0)
  k_gemm_nt<1,1><<<dim3(MLP/64, (NB*LE)/64), 256, 0, stream>>>(e_outputs, e_mlp_w, e_mlp_b, eh, NB*LE, MLP, HID);
  // GRU recurrence -> d_outputs (8 slices/batch, unique-tag agent sync)
  k_gru<<<dim3(NB*8), 192, 0, stream>>>(GI, W_hh, b_hh, h0, dout, hbuf);
  // d_h = relu(d_outputs @ d_mlp_w^T + b)  (M=8192,N=256,K=512) -- 128-tile
  k_gemm_nt128<1,1><<<dim3(MLP/128, (NB*LD)/128), 256, 0, stream>>>(dout, d_mlp_w, d_mlp_b, dh, NB*LD, MLP, HID);
  // T[l] = d_h @ U[l]  (M=8192,N=256,K=256, batched over l)
  k_gemm_nn_T<<<dim3(MLP/64, (NB*LD)/64, NL), 256, 0, stream>>>(dh, U, T);
  // s_e, s_d
  k_bilinear<<<dim3((NB*LE+255)/256), 256, 0, stream>>>(W_e, eh, se, LE);
  k_bilinear<<<dim3((NB*LD+255)/256), 256, 0, stream>>>(W_d, dh, sd, LD);
  // out[b,d,e,l] = T[l,b,d,:]·e_h[b,e,:] + s_d + s_e + b_aff
  k_s2<<<dim3(5, LD/64, NB), 256, 0, stream>>>(T, eh, sd, se, b_aff, out);
}

// Round 13
// 2504.185 us; speedup vs baseline: 8.1650x; 1.0220x over previous
//
#include <hip/hip_runtime.h>
#include <hip/hip_fp16.h>
#include <math.h>

#define NB   32
#define LD   256
#define LE   258
#define HID  512
#define H3   1536
#define MLP  256
#define NL   4

typedef _Float16 h2 __attribute__((ext_vector_type(2)));

// ---------- init: zero h transport buffer (every launch, graph-safe) ----------
__global__ void k_init(uint32_t* __restrict__ hb){
  int i = blockIdx.x*256 + threadIdx.x;
  if (i < 2*NB*HID) hb[i] = 0u;   // tag 0; first wants start at 1 -> never match
}

// ---------------- GRU: 256 WGs = 32 batches x 8 slices ----------------
// Round-12 protocol (8-bit unique tags, agent relaxed) with WAVE-0-ONLY wide
// poll: lane l watches the 8 contiguous words of slice l>>3 via 4 dwordx2
// agent loads (224 loads/WG/iter vs 576), accepts all-8-fresh, writes LDS
// once. Own slice bypasses global (writers -> LDS direct). Waves 1-2 only
// prefetch GI and wait at the barrier.
__global__ __launch_bounds__(192,1)
void k_gru(const float* __restrict__ GI, const float* __restrict__ W_hh,
           const float* __restrict__ b_hh, const float* __restrict__ h0,
           float* __restrict__ dout,
           uint32_t* __restrict__ hbuf){    // 2*NB*HID u32 (double buffer)
  const int wg  = blockIdx.x;
  const int b   = wg >> 3, g = wg & 7;
  const int tid = threadIdx.x;
  const int sect = tid >> 6;                  // 0=r, 1=z, 2=n
  const int u    = tid & 63;
  const int c    = sect*HID + g*64 + u;       // gate row in [0,1536)

  __shared__ __align__(16) float h_lds[HID];
  __shared__ float zs[64], gs[64], ns[64];

  // --- prologue: W_hh[c][:] -> 256 f16x2 VGPRs (one-time, static indexing) ---
  h2 w[256];
  const float4* wr = (const float4*)(W_hh + (size_t)c*HID);
  #pragma unroll
  for (int i=0;i<128;i++){
    float4 v = wr[i];
    h2 p0; p0[0]=(_Float16)v.x; p0[1]=(_Float16)v.y;
    h2 p1; p1[0]=(_Float16)v.z; p1[1]=(_Float16)v.w;
    w[2*i] = p0; w[2*i+1] = p1;
  }
  const float bh = b_hh[c];
  float h_old = (tid < 64) ? h0[(size_t)b*HID + g*64 + u] : 0.f;
  const float* gi_base = GI + (size_t)b*LD*H3 + c;
  float* db = dout + (size_t)b*LD*HID + g*64;

  // initial h_0 straight from h0 (fp32, plain loads)
  for (int i=tid;i<HID;i+=192) h_lds[i] = h0[(size_t)b*HID + i];
  __syncthreads();

  float gi = gi_base[0];                      // GI for step 0
  for (int t=0;t<LD;t++){
    // gh[c] = sum_k W_hh[c][k] * h[k]  (f16 weight, fp32 h, 4 indep accums)
    float a0=0.f, a1=0.f, a2=0.f, a3=0.f;
    const float4* hl = (const float4*)h_lds;
    #pragma unroll
    for (int kk=0;kk<128;kk++){
      float4 hv = hl[kk];
      h2 q0 = w[2*kk], q1 = w[2*kk+1];
      a0 = fmaf((float)q0[0], hv.x, a0);
      a1 = fmaf((float)q0[1], hv.y, a1);
      a2 = fmaf((float)q1[0], hv.z, a2);
      a3 = fmaf((float)q1[1], hv.w, a3);
    }
    float hh = (a0+a1) + (a2+a3) + bh;
    if (sect==1)      zs[u] = gi + hh;
    else if (sect==2){ gs[u] = gi; ns[u] = hh; }
    float pre_r = gi + hh;                     // valid for sect==0
    __syncthreads();                           // SYNC1: zs/gs/ns ready, dots done

    if (t < LD-1){
      uint32_t* hb = hbuf + (size_t)((t+1)&1)*(NB*HID) + (size_t)b*HID;
      const uint32_t want = (uint32_t)(t+1) & 0xFFu;   // unique per run
      float gnext = gi_base[(size_t)(t+1)*H3];         // issue early, all threads
      if (tid < 64){
        float r = __builtin_amdgcn_rcpf(1.f + __expf(-pre_r));
        float z = __builtin_amdgcn_rcpf(1.f + __expf(-zs[u]));
        float x = gs[u] + r*ns[u];
        float e2 = __expf(2.f*x);
        float n = 1.f - 2.f*__builtin_amdgcn_rcpf(e2 + 1.f);   // tanh
        float hnew = (1.f-z)*n + z*h_old;
        h_old = hnew;
        uint32_t wb = (__builtin_bit_cast(uint32_t, hnew) & ~0xFFu) | want;
        // own slice straight to LDS (skip own mall round-trip)
        ((uint32_t*)h_lds)[g*64 + u] = wb;
        __hip_atomic_store(hb + g*64 + u, wb,
                           __ATOMIC_RELAXED, __HIP_MEMORY_SCOPE_AGENT);
        db[(size_t)t*HID + u] = hnew;          // off critical path

        // ---- wave-0 wide poll: lane tid watches slice (tid>>3) ----
        const int sl = tid >> 3;
        bool pend = (sl != g);
        const unsigned long long* p =
            (const unsigned long long*)(hb + tid*8);
        int it = 0;
        while (__any(pend) && it < (1<<20)){
          if (pend){
            unsigned long long q0 = __hip_atomic_load(p+0, __ATOMIC_RELAXED, __HIP_MEMORY_SCOPE_AGENT);
            unsigned long long q1 = __hip_atomic_load(p+1, __ATOMIC_RELAXED, __HIP_MEMORY_SCOPE_AGENT);
            unsigned long long q2 = __hip_atomic_load(p+2, __ATOMIC_RELAXED, __HIP_MEMORY_SCOPE_AGENT);
            unsigned long long q3 = __hip_atomic_load(p+3, __ATOMIC_RELAXED, __HIP_MEMORY_SCOPE_AGENT);
            uint32_t t0=(uint32_t)q0, t1=(uint32_t)(q0>>32);
            uint32_t t2=(uint32_t)q1, t3=(uint32_t)(q1>>32);
            uint32_t t4=(uint32_t)q2, t5=(uint32_t)(q2>>32);
            uint32_t t6=(uint32_t)q3, t7=(uint32_t)(q3>>32);
            bool ok = ((t0&0xFFu)==want) & ((t1&0xFFu)==want)
                    & ((t2&0xFFu)==want) & ((t3&0xFFu)==want)
                    & ((t4&0xFFu)==want) & ((t5&0xFFu)==want)
                    & ((t6&0xFFu)==want) & ((t7&0xFFu)==want);
            if (ok){
              uint32_t* d = (uint32_t*)h_lds + tid*8;
              d[0]=t0; d[1]=t1; d[2]=t2; d[3]=t3;
              d[4]=t4; d[5]=t5; d[6]=t6; d[7]=t7;
              pend = false;
            }
          }
          ++it;
          __builtin_amdgcn_s_sleep(1);
        }
      }
      __syncthreads();                         // SYNC2: h_lds fully fresh
      gi = gnext;
    } else {
      if (tid < 64){
        float r = __builtin_amdgcn_rcpf(1.f + __expf(-pre_r));
        float z = __builtin_amdgcn_rcpf(1.f + __expf(-zs[u]));
        float x = gs[u] + r*ns[u];
        float e2 = __expf(2.f*x);
        float n = 1.f - 2.f*__builtin_amdgcn_rcpf(e2 + 1.f);
        float hnew = (1.f-z)*n + z*h_old;
        db[(size_t)t*HID + u] = hnew;
      }
    }
  }
}

// ---- big NT gemm: C[M,N] = A[M,K]@B[N,K]^T (+bias)(+relu), 128x128 tile ----
template<int BIAS, int RELU>
__global__ __launch_bounds__(256)
void k_gemm_nt128(const float* __restrict__ A, const float* __restrict__ Bm,
                  const float* __restrict__ bias, float* __restrict__ C,
                  int M, int N, int K){
  __shared__ float As[16][132];
  __shared__ float Bs[16][132];
  const int bm = blockIdx.y*128, bn = blockIdx.x*128;
  const int tid = threadIdx.x;
  const int tx = tid & 15, ty = tid >> 4;      // 16x16 thread grid
  const int lr = tid >> 1;                     // 0..127 load row
  const int lc = (tid & 1) << 3;               // 0 or 8
  const float* Ap = A + (size_t)(bm+lr)*K + lc;
  const float* Bp = Bm + (size_t)(bn+lr)*K + lc;
  float acc[8][8] = {};
  for (int k0=0;k0<K;k0+=16){
    float4 a0 = *(const float4*)(Ap + k0);
    float4 a1 = *(const float4*)(Ap + k0 + 4);
    float4 b0 = *(const float4*)(Bp + k0);
    float4 b1 = *(const float4*)(Bp + k0 + 4);
    __syncthreads();
    As[lc+0][lr]=a0.x; As[lc+1][lr]=a0.y; As[lc+2][lr]=a0.z; As[lc+3][lr]=a0.w;
    As[lc+4][lr]=a1.x; As[lc+5][lr]=a1.y; As[lc+6][lr]=a1.z; As[lc+7][lr]=a1.w;
    Bs[lc+0][lr]=b0.x; Bs[lc+1][lr]=b0.y; Bs[lc+2][lr]=b0.z; Bs[lc+3][lr]=b0.w;
    Bs[lc+4][lr]=b1.x; Bs[lc+5][lr]=b1.y; Bs[lc+6][lr]=b1.z; Bs[lc+7][lr]=b1.w;
    __syncthreads();
    #pragma unroll
    for (int kk=0;kk<16;kk++){
      float4 va0 = *(const float4*)&As[kk][ty<<3];
      float4 va1 = *(const float4*)&As[kk][(ty<<3)+4];
      float4 vb0 = *(const float4*)&Bs[kk][tx<<3];
      float4 vb1 = *(const float4*)&Bs[kk][(tx<<3)+4];
      float a8[8] = {va0.x,va0.y,va0.z,va0.w,va1.x,va1.y,va1.z,va1.w};
      float b8[8] = {vb0.x,vb0.y,vb0.z,vb0.w,vb1.x,vb1.y,vb1.z,vb1.w};
      #pragma unroll
      for (int i=0;i<8;i++)
        #pragma unroll
        for (int j=0;j<8;j++)
          acc[i][j] = fmaf(a8[i], b8[j], acc[i][j]);
    }
  }
  #pragma unroll
  for (int i=0;i<8;i++){
    int m = bm + (ty<<3) + i;
    #pragma unroll
    for (int j=0;j<8;j++){
      int n = bn + (tx<<3) + j;
      float v = acc[i][j];
      if (BIAS) v += bias[n];
      if (RELU) v = fmaxf(v, 0.f);
      C[(size_t)m*N + n] = v;
    }
  }
}

// ---------- generic NT gemm (64x64): used where M%128 != 0 (e_h) ----------
template<int BIAS, int RELU>
__global__ __launch_bounds__(256)
void k_gemm_nt(const float* __restrict__ A, const float* __restrict__ Bm,
               const float* __restrict__ bias, float* __restrict__ C,
               int M, int N, int K){
  __shared__ float As[32][68];
  __shared__ float Bs[32][68];
  const int bm = blockIdx.y*64, bn = blockIdx.x*64;
  const int tid = threadIdx.x;
  const int tx = tid & 15, ty = tid >> 4;
  const int lr = tid >> 3;
  const int lk = (tid & 7) << 2;
  const float* A0 = A + (size_t)(bm+lr)*K + lk;
  const float* A1 = A + (size_t)(bm+lr+32)*K + lk;
  const float* B0 = Bm + (size_t)(bn+lr)*K + lk;
  const float* B1 = Bm + (size_t)(bn+lr+32)*K + lk;
  float acc[4][4] = {};
  for (int k0=0;k0<K;k0+=32){
    float4 a0 = *(const float4*)(A0 + k0);
    float4 a1 = *(const float4*)(A1 + k0);
    float4 b0 = *(const float4*)(B0 + k0);
    float4 b1 = *(const float4*)(B1 + k0);
    __syncthreads();
    As[lk+0][lr]=a0.x; As[lk+1][lr]=a0.y; As[lk+2][lr]=a0.z; As[lk+3][lr]=a0.w;
    As[lk+0][lr+32]=a1.x; As[lk+1][lr+32]=a1.y; As[lk+2][lr+32]=a1.z; As[lk+3][lr+32]=a1.w;
    Bs[lk+0][lr]=b0.x; Bs[lk+1][lr]=b0.y; Bs[lk+2][lr]=b0.z; Bs[lk+3][lr]=b0.w;
    Bs[lk+0][lr+32]=b1.x; Bs[lk+1][lr+32]=b1.y; Bs[lk+2][lr+32]=b1.z; Bs[lk+3][lr+32]=b1.w;
    __syncthreads();
    #pragma unroll
    for (int kk=0;kk<32;kk++){
      float4 av = *(const float4*)&As[kk][ty<<2];
      float4 bv = *(const float4*)&Bs[kk][tx<<2];
      float a4[4] = {av.x,av.y,av.z,av.w};
      float b4[4] = {bv.x,bv.y,bv.z,bv.w};
      #pragma unroll
      for (int i=0;i<4;i++)
        #pragma unroll
        for (int j=0;j<4;j++)
          acc[i][j] = fmaf(a4[i], b4[j], acc[i][j]);
    }
  }
  #pragma unroll
  for (int i=0;i<4;i++){
    int m = bm + (ty<<2) + i;
    #pragma unroll
    for (int j=0;j<4;j++){
      int n = bn + (tx<<2) + j;
      float v = acc[i][j];
      if (BIAS) v += bias[n];
      if (RELU) v = fmaxf(v, 0.f);
      C[(size_t)m*N + n] = v;
    }
  }
}

// ---------- NN gemm (batched over l): T[l][b][d][k] = d_h @ U[l] ----------
__global__ __launch_bounds__(256)
void k_gemm_nn_T(const float* __restrict__ A, const float* __restrict__ U,
                 float* __restrict__ T){
  __shared__ float As[32][68];
  __shared__ float Bs[32][68];
  const int l = blockIdx.z;
  const float* Bm = U + (size_t)l*MLP*MLP;
  float* C = T + (size_t)l*NB*LD*MLP;
  const int bm = blockIdx.y*64, bn = blockIdx.x*64;
  const int tid = threadIdx.x;
  const int tx = tid & 15, ty = tid >> 4;
  const int lr = tid >> 3;
  const int lk = (tid & 7) << 2;
  const int bk_r = tid >> 4;
  const int bn_c = (tid & 15) << 2;
  const float* A0 = A + (size_t)(bm+lr)*MLP + lk;
  const float* A1 = A + (size_t)(bm+lr+32)*MLP + lk;
  float acc[4][4] = {};
  for (int k0=0;k0<MLP;k0+=32){
    float4 a0 = *(const float4*)(A0 + k0);
    float4 a1 = *(const float4*)(A1 + k0);
    float4 u0 = *(const float4*)(Bm + (size_t)(k0+bk_r)*MLP + bn + bn_c);
    float4 u1 = *(const float4*)(Bm + (size_t)(k0+bk_r+16)*MLP + bn + bn_c);
    __syncthreads();
    As[lk+0][lr]=a0.x; As[lk+1][lr]=a0.y; As[lk+2][lr]=a0.z; As[lk+3][lr]=a0.w;
    As[lk+0][lr+32]=a1.x; As[lk+1][lr+32]=a1.y; As[lk+2][lr+32]=a1.z; As[lk+3][lr+32]=a1.w;
    *(float4*)&Bs[bk_r][bn_c]    = u0;
    *(float4*)&Bs[bk_r+16][bn_c] = u1;
    __syncthreads();
    #pragma unroll
    for (int kk=0;kk<32;kk++){
      float4 av = *(const float4*)&As[kk][ty<<2];
      float4 bv = *(const float4*)&Bs[kk][tx<<2];
      float a4[4] = {av.x,av.y,av.z,av.w};
      float b4[4] = {bv.x,bv.y,bv.z,bv.w};
      #pragma unroll
      for (int i=0;i<4;i++)
        #pragma unroll
        for (int j=0;j<4;j++)
          acc[i][j] = fmaf(a4[i], b4[j], acc[i][j]);
    }
  }
  #pragma unroll
  for (int i=0;i<4;i++){
    int m = bm + (ty<<2) + i;
    #pragma unroll
    for (int j=0;j<4;j++)
      C[(size_t)m*MLP + bn + (tx<<2) + j] = acc[i][j];
  }
}

// -------- s_e / s_d: S[b][l][r] = dot(W[l], Hm[b,r,:]) --------
__global__ void k_bilinear(const float* __restrict__ W, const float* __restrict__ Hm,
                           float* __restrict__ S, int Lrows){
  int idx = blockIdx.x*256 + threadIdx.x;
  if (idx >= NB*Lrows) return;
  int b = idx / Lrows, r = idx - b*Lrows;
  const float* row = Hm + (size_t)idx*MLP;
  float acc[NL] = {0.f,0.f,0.f,0.f};
  for (int h=0; h<MLP; h+=4){
    float4 x = *(const float4*)(row + h);
    #pragma unroll
    for (int l=0;l<NL;l++){
      float4 w = *(const float4*)(W + l*MLP + h);
      acc[l] += x.x*w.x + x.y*w.y + x.z*w.z + x.w*w.w;
    }
  }
  #pragma unroll
  for (int l=0;l<NL;l++) S[((size_t)b*NL + l)*Lrows + r] = acc[l];
}

// -------- final: out[b,d,e,l] = T[l,b,d,:]·e_h[b,e,:] + s_d + s_e + b_aff --------
__global__ __launch_bounds__(256)
void k_s2(const float* __restrict__ T, const float* __restrict__ eh,
          const float* __restrict__ sd, const float* __restrict__ se,
          const float* __restrict__ baff, float* __restrict__ out){
  __shared__ float As[32][68];
  __shared__ float Bs[32][68];
  const int b = blockIdx.z;
  const int d0 = blockIdx.y*64, e0 = blockIdx.x*64;
  const int tid = threadIdx.x;
  const int tx = tid & 15, ty = tid >> 4;
  const int lr = tid >> 3;
  const int lk = (tid & 7) << 2;
  const float* EH = eh + (size_t)b*LE*MLP;
  for (int l=0;l<NL;l++){
    const float* A = T + ((size_t)(l*NB + b))*LD*MLP;
    float acc[4][4] = {};
    for (int k0=0;k0<MLP;k0+=32){
      float4 a0 = *(const float4*)(A + (size_t)(d0+lr)*MLP + k0 + lk);
      float4 a1 = *(const float4*)(A + (size_t)(d0+lr+32)*MLP + k0 + lk);
      float4 z4 = make_float4(0.f,0.f,0.f,0.f);
      int er0 = e0+lr, er1 = e0+lr+32;
      float4 b0 = (er0<LE) ? *(const float4*)(EH + (size_t)er0*MLP + k0 + lk) : z4;
      float4 b1 = (er1<LE) ? *(const float4*)(EH + (size_t)er1*MLP + k0 + lk) : z4;
      __syncthreads();
      As[lk+0][lr]=a0.x; As[lk+1][lr]=a0.y; As[lk+2][lr]=a0.z; As[lk+3][lr]=a0.w;
      As[lk+0][lr+32]=a1.x; As[lk+1][lr+32]=a1.y; As[lk+2][lr+32]=a1.z; As[lk+3][lr+32]=a1.w;
      Bs[lk+0][lr]=b0.x; Bs[lk+1][lr]=b0.y; Bs[lk+2][lr]=b0.z; Bs[lk+3][lr]=b0.w;
      Bs[lk+0][lr+32]=b1.x; Bs[lk+1][lr+32]=b1.y; Bs[lk+2][lr+32]=b1.z; Bs[lk+3][lr+32]=b1.w;
      __syncthreads();
      #pragma unroll
      for (int kk=0;kk<32;kk++){
        float4 av = *(const float4*)&As[kk][ty<<2];
        float4 bv = *(const float4*)&Bs[kk][tx<<2];
        float a4[4] = {av.x,av.y,av.z,av.w};
        float b4[4] = {bv.x,bv.y,bv.z,bv.w};
        #pragma unroll
        for (int i=0;i<4;i++)
          #pragma unroll
          for (int j=0;j<4;j++)
            acc[i][j] = fmaf(a4[i], b4[j], acc[i][j]);
      }
    }
    float bl = baff[l];
    float sdl[4], sel[4];
    #pragma unroll
    for (int i=0;i<4;i++) sdl[i] = sd[((size_t)b*NL + l)*LD + d0 + (ty<<2) + i];
    #pragma unroll
    for (int j=0;j<4;j++){
      int e = e0 + (tx<<2) + j;
      sel[j] = (e<LE) ? se[((size_t)b*NL + l)*LE + e] : 0.f;
    }
    #pragma unroll
    for (int i=0;i<4;i++){
      int d = d0 + (ty<<2) + i;
      #pragma unroll
      for (int j=0;j<4;j++){
        int e = e0 + (tx<<2) + j;
        if (e < LE)
          out[(((size_t)b*LD + d)*LE + e)*NL + l] = acc[i][j] + sdl[i] + sel[j] + bl;
      }
    }
  }
}

extern "C" void kernel_launch(void* const* d_in, const int* in_sizes, int n_in,
                              void* d_out, int out_size, void* d_ws, size_t ws_size,
                              hipStream_t stream){
  const float* e_outputs = (const float*)d_in[0];
  const float* d_inputs  = (const float*)d_in[1];
  const float* h0        = (const float*)d_in[2];
  const float* W_ih      = (const float*)d_in[3];
  const float* W_hh      = (const float*)d_in[4];
  const float* b_ih      = (const float*)d_in[5];
  const float* b_hh      = (const float*)d_in[6];
  const float* e_mlp_w   = (const float*)d_in[7];
  const float* e_mlp_b   = (const float*)d_in[8];
  const float* d_mlp_w   = (const float*)d_in[9];
  const float* d_mlp_b   = (const float*)d_in[10];
  const float* W_e       = (const float*)d_in[11];
  const float* W_d       = (const float*)d_in[12];
  const float* U         = (const float*)d_in[13];
  const float* b_aff     = (const float*)d_in[14];
  float* out = (float*)d_out;
  float* ws  = (float*)d_ws;

  // workspace layout (floats). T reuses GI's region (GI dead after k_gru).
  float* GI   = ws;                        // 32*256*1536 = 12,582,912
  float* T    = ws;                        // 4*32*256*256 = 8,388,608 (overlaps GI)
  uint32_t* hbuf = (uint32_t*)(ws + 12582912);  // 2*32*512 u32
  float* dout = ws   + 12582912 + 786432;  // 32*256*512 = 4,194,304
  float* eh   = dout + 4194304;            // 32*258*256 = 2,113,536
  float* dh   = eh   + 2113536;            // 32*256*256 = 2,097,152
  float* se   = dh   + 2097152;            // 32*4*258 = 33,024
  float* sd   = se   + 33024;              // 32*4*256 = 32,768

  k_init<<<dim3((2*NB*HID+255)/256), 256, 0, stream>>>(hbuf);
  // GI = d_inputs @ W_ih^T + b_ih   (M=8192,N=1536,K=512) -- 128-tile
  k_gemm_nt128<1,0><<<dim3(H3/128, (NB*LD)/128), 256, 0, stream>>>(d_inputs, W_ih, b_ih, GI, NB*LD, H3, HID);
  // e_h = relu(e_outputs @ e_mlp_w^T + b)  (M=8256,N=256,K=512) -- 64-tile
  k_gemm_nt<1,1><<<dim3(MLP/64, (NB*LE)/64), 256, 0, stream>>>(e_outputs, e_mlp_w, e_mlp_b, eh, NB*LE, MLP, HID);
  // GRU recurrence -> d_outputs (8 slices/batch, wave-0 wide poll, unique tags)
  k_gru<<<dim3(NB*8), 192, 0, stream>>>(GI, W_hh, b_hh, h0, dout, hbuf);
  // d_h = relu(d_outputs @ d_mlp_w^T + b)  (M=8192,N=256,K=512) -- 128-tile
  k_gemm_nt128<1,1><<<dim3(MLP/128, (NB*LD)/128), 256, 0, stream>>>(dout, d_mlp_w, d_mlp_b, dh, NB*LD, MLP, HID);
  // T[l] = d_h @ U[l]  (M=8192,N=256,K=256, batched over l)
  k_gemm_nn_T<<<dim3(MLP/64, (NB*LD)/64, NL), 256, 0, stream>>>(dh, U, T);
  // s_e, s_d
  k_bilinear<<<dim3((NB*LE+255)/256), 256, 0, stream>>>(W_e, eh, se, LE);
  k_bilinear<<<dim3((NB*LD+255)/256), 256, 0, stream>>>(W_d, dh, sd, LD);
  // out[b,d,e,l] = T[l,b,d,:]·e_h[b,e,:] + s_d + s_e + b_aff
  k_s2<<<dim3(5, LD/64, NB), 256, 0, stream>>>(T, eh, sd, se, b_aff, out);
}